// Round 2
// baseline (620.019 us; speedup 1.0000x reference)
//
#include <hip/hip_runtime.h>
#include <math.h>

#define BATCH 65536
#define EMBED 128
#define HIST 5
#define NEG 2
#define LPE 32   // lanes per element; 1 float4 per lane covers the 512B row

__device__ __forceinline__ float sqd4(const float4& p, const float4& q) {
    float d0 = p.x - q.x;
    float d1 = p.y - q.y;
    float d2 = p.z - q.z;
    float d3 = p.w - q.w;
    return d0*d0 + d1*d1 + d2*d2 + d3*d3;
}

__device__ __forceinline__ float logsig(float z) {
    // stable log_sigmoid: min(z,0) - log1p(exp(-|z|))
    return fminf(z, 0.0f) - log1pf(expf(-fabsf(z)));
}

__global__ __launch_bounds__(256) void htne_kernel(
    const int*   __restrict__ xs,
    const int*   __restrict__ ys,
    const float* __restrict__ e_times,
    const int*   __restrict__ hs,
    const float* __restrict__ h_times,
    const int*   __restrict__ neg,
    const float* __restrict__ mask,
    const float* __restrict__ emb,
    const float* __restrict__ delta_tab,
    float*       __restrict__ out)
{
    const int tid = blockIdx.x * blockDim.x + threadIdx.x;
    const int e   = tid >> 5;                 // element index (32 lanes/element)
    const int sub = threadIdx.x & (LPE - 1);  // lane within element group
    if (e >= BATCH) return;

    const float4* embv = (const float4*)emb;  // 32 float4 per row

    // --- row indices (broadcast within the 32-lane group)
    const int xrow = xs[e];
    const int yrow = ys[e];
    int hrow[HIST];
#pragma unroll
    for (int i = 0; i < HIST; ++i) hrow[i] = hs[e * HIST + i];
    int nrow[NEG];
#pragma unroll
    for (int j = 0; j < NEG; ++j) nrow[j] = neg[e * NEG + j];

    // --- epilogue scalars: issue early so they overlap the row gathers
    const float et    = e_times[e];
    const float delta = delta_tab[xrow];
    float ht[HIST], hm[HIST];
#pragma unroll
    for (int i = 0; i < HIST; ++i) {
        ht[i] = h_times[e * HIST + i];
        hm[i] = mask[e * HIST + i];
    }

    // --- 9 contiguous float4 gathers, all in flight together (36 VGPRs of data)
    float4 x, y, h[HIST], nn[NEG];
    x = embv[(size_t)xrow * 32 + sub];
    y = embv[(size_t)yrow * 32 + sub];
#pragma unroll
    for (int i = 0; i < HIST; ++i) h[i]  = embv[(size_t)hrow[i] * 32 + sub];
#pragma unroll
    for (int j = 0; j < NEG; ++j)  nn[j] = embv[(size_t)nrow[j] * 32 + sub];

    // --- 18 per-lane partial squared distances
    // r[0]           : ||x-y||^2
    // r[1..5]        : ||x-h_i||^2
    // r[6..7]        : ||x-n_j||^2
    // r[8 + i*2 + j] : ||h_i-n_j||^2
    float r[18];
    r[0] = sqd4(x, y);
#pragma unroll
    for (int i = 0; i < HIST; ++i) r[1 + i] = sqd4(x, h[i]);
#pragma unroll
    for (int j = 0; j < NEG; ++j) r[6 + j] = sqd4(x, nn[j]);
#pragma unroll
    for (int i = 0; i < HIST; ++i)
#pragma unroll
        for (int j = 0; j < NEG; ++j) r[8 + i * 2 + j] = sqd4(h[i], nn[j]);

    // --- butterfly reduce across the 32-lane group (5 steps)
#pragma unroll
    for (int i = 0; i < 18; ++i) {
#pragma unroll
        for (int m = 1; m < LPE; m <<= 1) {
            r[i] += __shfl_xor(r[i], m, 64);
        }
    }

    // --- scalar epilogue (all 32 lanes redundantly; no divergence)
    const float p_mu = -r[0];

    float alpha[HIST];
#pragma unroll
    for (int i = 0; i < HIST; ++i) alpha[i] = -r[1 + i];

    float mx = alpha[0];
#pragma unroll
    for (int i = 1; i < HIST; ++i) mx = fmaxf(mx, alpha[i]);

    float ex[HIST];
    float s = 0.0f;
#pragma unroll
    for (int i = 0; i < HIST; ++i) { ex[i] = expf(alpha[i] - mx); s += ex[i]; }
    const float inv_s = 1.0f / s;

    float w[HIST];
    float p_acc = 0.0f;
#pragma unroll
    for (int i = 0; i < HIST; ++i) {
        const float dt    = fabsf(et - ht[i]);
        const float decay = expf(delta * dt) * hm[i];
        w[i] = ex[i] * inv_s * decay;   // attn * decay
        p_acc += w[i] * alpha[i];
    }
    const float p_lambda = p_mu + p_acc;

    float loss = logsig(p_lambda);
#pragma unroll
    for (int j = 0; j < NEG; ++j) {
        float nl = -r[6 + j];
#pragma unroll
        for (int i = 0; i < HIST; ++i) nl += w[i] * (-r[8 + i * 2 + j]);
        loss -= logsig(nl);
    }

    if (sub == 0) out[e] = loss;
}

extern "C" void kernel_launch(void* const* d_in, const int* in_sizes, int n_in,
                              void* d_out, int out_size, void* d_ws, size_t ws_size,
                              hipStream_t stream) {
    const int*   xs        = (const int*)  d_in[0];
    const int*   ys        = (const int*)  d_in[1];
    const float* e_times   = (const float*)d_in[2];
    const int*   hs        = (const int*)  d_in[3];
    const float* h_times   = (const float*)d_in[4];
    const int*   neg       = (const int*)  d_in[5];
    const float* mask      = (const float*)d_in[6];
    const float* emb       = (const float*)d_in[7];
    const float* delta_tab = (const float*)d_in[8];
    float*       out       = (float*)d_out;

    const int threads = 256;                      // 8 elements per block
    const int blocks  = (BATCH * LPE) / threads;  // 8192
    htne_kernel<<<blocks, threads, 0, stream>>>(
        xs, ys, e_times, hs, h_times, neg, mask, emb, delta_tab, out);
}